// Round 13
// baseline (809.211 us; speedup 1.0000x reference)
//
#include <hip/hip_runtime.h>

#define Bsz 1024
#define Tn  256
#define Fn  128

typedef float f32x4 __attribute__((ext_vector_type(4)));
typedef float v2f   __attribute__((ext_vector_type(2)));
typedef short s16x8 __attribute__((ext_vector_type(8)));

#define LOG2E 1.44269504088896f
#define L2E2  2.88539008177793f

__device__ __forceinline__ float frcp(float x)  { return __builtin_amdgcn_rcpf(x); }
__device__ __forceinline__ unsigned bf16bits(float v) {   // RNE f32 -> bf16 bits
    unsigned x = __float_as_uint(v);
    return (x + 0x7FFFu + ((x >> 16) & 1u)) >> 16;
}
__device__ __forceinline__ float fromhi(unsigned hb) { return __uint_as_float(hb << 16); }
__device__ __forceinline__ unsigned cvtpk(float a, float b) {  // low=bf16(a), high=bf16(b)
    unsigned r; asm("v_cvt_pk_bf16_f32 %0, %1, %2" : "=v"(r) : "v"(a), "v"(b)); return r;
}

// ---------- forced VOP3P packed fp32 (2 results/lane, same issue slot) ----------
__device__ __forceinline__ v2f pk_add(v2f a, v2f b) {
    v2f d; asm("v_pk_add_f32 %0, %1, %2" : "=v"(d) : "v"(a), "v"(b)); return d;
}
__device__ __forceinline__ v2f pk_sub(v2f a, v2f b) {   // a - b via neg modifier
    v2f d; asm("v_pk_add_f32 %0, %1, %2 neg_lo:[0,1] neg_hi:[0,1]"
               : "=v"(d) : "v"(a), "v"(b)); return d;
}
__device__ __forceinline__ v2f pk_mul(v2f a, v2f b) {
    v2f d; asm("v_pk_mul_f32 %0, %1, %2" : "=v"(d) : "v"(a), "v"(b)); return d;
}
__device__ __forceinline__ v2f pk_fma(v2f a, v2f b, v2f c) {
    v2f d; asm("v_pk_fma_f32 %0, %1, %2, %3" : "=v"(d) : "v"(a), "v"(b), "v"(c)); return d;
}

union FragU { unsigned u[4]; s16x8 v; };

// packed constants (held in VGPRs across the loop; VOP3P can't take literals)
struct PkC { v2f magic, k5, k4, k3, k2, k1, one, l2e2; };

// ---------- packed poly exp2: 2^g for a PAIR, ~8 pk + 2 fused scalar ops ----------
// t = RNE(g+1.5*2^23); r = t-magic (exact int part); f = g-r in [-.5,.5];
// 2^g = poly5(f) * 2^r with 2^r folded in via (bits(t)<<23) integer add
// (magic's low 9 mantissa bits are 0). Domain: -126 <= g <= ~100.
__device__ __forceinline__ v2f pk_exp2(v2f g, const PkC& K) {
    const v2f t = pk_add(g, K.magic);
    const v2f r = pk_sub(t, K.magic);
    const v2f f = pk_sub(g, r);
    v2f p = pk_fma(f, K.k5, K.k4);
    p = pk_fma(p, f, K.k3);
    p = pk_fma(p, f, K.k2);
    p = pk_fma(p, f, K.k1);
    p = pk_fma(p, f, K.one);
    return v2f{__uint_as_float(__float_as_uint(p.x) + (__float_as_uint(t.x) << 23)),
               __uint_as_float(__float_as_uint(p.y) + (__float_as_uint(t.y) << 23))};
}

// ---------- packed 2-cell LSTM activation (exp2 domain, all-VALU) ----------
// Gate bounds (|W|<=1.04 scaled, |h|<1, |x|<=6): |gi,gf,go|<=14, gg<=27 ->
// exp2p domain safe without clamps; only cs (c*2log2e, |c| can random-walk)
// is clamped to [-126,40] so the exponent bit-add cannot wrap.
__device__ __forceinline__ v2f act_pair(v2f gi, v2f gf, v2f gg, v2f go,
                                        v2f& c2, const PkC& K) {
    const v2f Ei = pk_exp2(gi, K);
    const v2f Ef = pk_exp2(gf, K);
    const v2f Eg = pk_exp2(gg, K);
    const v2f Eo = pk_exp2(go, K);
    const v2f pf  = pk_add(K.one, Ef);
    const v2f pig = pk_mul(pk_add(K.one, Ei), pk_add(K.one, Eg));
    const v2f p3  = pk_mul(pig, pf);
    const float Rm = frcp(p3.x * p3.y);            // pair-shared reciprocal
    const v2f R3  = {Rm * p3.y, Rm * p3.x};
    const v2f Rf  = pk_mul(pig, R3);               // sigmoid(f)
    const v2f Rig = pk_mul(pf,  R3);               // 1/((1+Ei)(1+Eg))
    const v2f cn  = pk_fma(c2, Rf, pk_mul(pk_sub(Eg, K.one), Rig));
    c2 = cn;
    const v2f csp = pk_mul(cn, K.l2e2);
    const v2f cs  = {fmaxf(fminf(csp.x, 40.0f), -126.0f),   // VOP2 literals, no regs
                     fmaxf(fminf(csp.y, 40.0f), -126.0f)};
    const v2f Ec  = pk_exp2(cs, K);
    const v2f den = pk_mul(pk_add(K.one, Eo), pk_add(K.one, Ec));
    const float Rd = frcp(den.x * den.y);          // pair-shared reciprocal
    const v2f Roc = {Rd * den.y, Rd * den.x};
    return pk_mul(pk_sub(Ec, K.one), Roc);         // o * tanh(c)
}

// ---------- kernel 1: transpose x (B,T,F) f32 -> (T,F,B) packed (lo16<<16 | hi16) ----------
__global__ __launch_bounds__(256) void transpose_pack(const float* __restrict__ x,
                                                      unsigned* __restrict__ xt) {
    __shared__ float tile[32][33];
    const int t  = blockIdx.z;
    const int bb = blockIdx.x * 32;
    const int ff = blockIdx.y * 32;
    const int tx = threadIdx.x;   // 0..31
    const int ty = threadIdx.y;   // 0..7
#pragma unroll
    for (int i = 0; i < 4; ++i) {
        int brow = ty + i * 8;
        tile[brow][tx] = x[((size_t)(bb + brow) * Tn + t) * Fn + (ff + tx)];
    }
    __syncthreads();
#pragma unroll
    for (int i = 0; i < 4; ++i) {
        int frow = ty + i * 8;
        float v = tile[tx][frow];
        unsigned hb = bf16bits(v);
        unsigned lb = bf16bits(v - fromhi(hb));
        xt[((size_t)t * Fn + (ff + frow)) * Bsz + (bb + tx)] = hb | (lb << 16);
    }
}

// ---------- kernel 2: recurrent LSTM via MFMA, zero LDS, 4 MFMA/step ----------
// (structure validated r12, absmax 4.9e-4)
__global__ __launch_bounds__(256, 4) void lstm_fwd(const unsigned* __restrict__ xt,  // (T,F,B) packed
                                                   const float* __restrict__ Wih,    // (F,64)
                                                   const float* __restrict__ Whh,    // (F,64,16)
                                                   const float* __restrict__ bih,    // (F,64)
                                                   const float* __restrict__ bhh,    // (F,64)
                                                   const float* __restrict__ init_h,
                                                   const float* __restrict__ init_c,
                                                   float* __restrict__ hout) {       // (B, F*16)
    const int tid  = threadIdx.x;
    const int wv   = tid >> 6;
    const int lane = tid & 63;
    const int gq   = lane >> 4;          // k-quad group / D-row-group
    const int col  = lane & 15;          // A: M-row; B,D: batch col
    const int f    = blockIdx.x >> 4;
    const int bc   = ((blockIdx.x & 15) << 2) | wv;
    const int bglob = bc * 16 + col;

    // ---- persistent fragments (weights pre-scaled into exp2 domain) ----
    s16x8 Aw[4];
    f32x4 biasC[4];
#pragma unroll
    for (int g = 0; g < 4; ++g) {
        const float s = (g == 2) ? L2E2 : -LOG2E;
        const float* wrow = Whh + ((size_t)f * 64 + g * 16 + col) * 16;
        float v0 = wrow[4 * gq + 0] * s, v1 = wrow[4 * gq + 1] * s;
        float v2 = wrow[4 * gq + 2] * s, v3 = wrow[4 * gq + 3] * s;
        unsigned h0 = bf16bits(v0), h1 = bf16bits(v1);
        unsigned h2 = bf16bits(v2), h3 = bf16bits(v3);
        FragU a;
        a.u[0] = h0 | (h1 << 16);        // W_hi quad (plane 0)
        a.u[1] = h2 | (h3 << 16);
        if (gq < 2) {                    // plane 1: W_lo quad
            a.u[2] = bf16bits(v0 - fromhi(h0)) | (bf16bits(v1 - fromhi(h1)) << 16);
            a.u[3] = bf16bits(v2 - fromhi(h2)) | (bf16bits(v3 - fromhi(h3)) << 16);
        } else {                         // plane 1: x-slots
            const float wx = Wih[(size_t)f * 64 + g * 16 + col] * s;
            const unsigned wxh = bf16bits(wx);
            const unsigned wxl = bf16bits(wx - fromhi(wxh));
            a.u[2] = (gq == 2) ? (wxh | (wxh << 16))   // wxh*x_hi + wxh*x_lo
                               : wxl;                  // wxl*x_hi
            a.u[3] = 0u;
        }
        Aw[g] = a.v;
        const size_t bb = (size_t)f * 64 + g * 16 + gq * 4;
        biasC[g] = f32x4{(bih[bb + 0] + bhh[bb + 0]) * s, (bih[bb + 1] + bhh[bb + 1]) * s,
                         (bih[bb + 2] + bhh[bb + 2]) * s, (bih[bb + 3] + bhh[bb + 3]) * s};
    }

    const PkC K = {(v2f)12582912.0f, (v2f)0.0013333558f, (v2f)0.0096181291f,
                   (v2f)0.0555041086f, (v2f)0.2402265069f, (v2f)0.6931471806f,
                   (v2f)1.0f, (v2f)L2E2};

    v2f c01, c23, h01, h23;
    {
        const int base = f * 16 + gq * 4;
        c01 = v2f{init_c[base + 0], init_c[base + 1]};
        c23 = v2f{init_c[base + 2], init_c[base + 3]};
        h01 = v2f{init_h[base + 0], init_h[base + 1]};
        h23 = v2f{init_h[base + 2], init_h[base + 3]};
    }

    unsigned p0 = cvtpk(h01.x, h01.y);
    unsigned p1 = cvtpk(h23.x, h23.y);

    const bool hpath = (gq < 2);         // B plane-1 content select
    const unsigned* __restrict__ xp = xt + (size_t)f * Bsz + bglob;
    unsigned xw = xp[0];

    for (int t = 0; t < Tn; ++t) {
        const unsigned xnext = xp[(t + 1 < Tn) ? Fn * Bsz : 0];
        xp += Fn * Bsz;

        FragU b;
        b.u[0] = p0;
        b.u[1] = p1;
        b.u[2] = hpath ? p0 : xw;
        b.u[3] = hpath ? p1 : 0u;

        const f32x4 acc0 = __builtin_amdgcn_mfma_f32_16x16x32_bf16(Aw[0], b.v, biasC[0], 0, 0, 0);
        const f32x4 acc1 = __builtin_amdgcn_mfma_f32_16x16x32_bf16(Aw[1], b.v, biasC[1], 0, 0, 0);
        const f32x4 acc2 = __builtin_amdgcn_mfma_f32_16x16x32_bf16(Aw[2], b.v, biasC[2], 0, 0, 0);
        const f32x4 acc3 = __builtin_amdgcn_mfma_f32_16x16x32_bf16(Aw[3], b.v, biasC[3], 0, 0, 0);

        h01 = act_pair(__builtin_shufflevector(acc0, acc0, 0, 1),
                       __builtin_shufflevector(acc1, acc1, 0, 1),
                       __builtin_shufflevector(acc2, acc2, 0, 1),
                       __builtin_shufflevector(acc3, acc3, 0, 1), c01, K);
        h23 = act_pair(__builtin_shufflevector(acc0, acc0, 2, 3),
                       __builtin_shufflevector(acc1, acc1, 2, 3),
                       __builtin_shufflevector(acc2, acc2, 2, 3),
                       __builtin_shufflevector(acc3, acc3, 2, 3), c23, K);

        p0 = cvtpk(h01.x, h01.y);
        p1 = cvtpk(h23.x, h23.y);
        xw = xnext;
    }

    *(f32x4*)(&hout[(size_t)bglob * (Fn * 16) + f * 16 + gq * 4]) =
        f32x4{h01.x, h01.y, h23.x, h23.y};
}

// ---------- kernel 3: out[b] = b_fuse + sum_k hout[b][k]*W_fuse[k] ----------
__global__ __launch_bounds__(256) void fuse_out(const float* __restrict__ hout,
                                                const float* __restrict__ Wf,
                                                const float* __restrict__ bfu,
                                                float* __restrict__ out) {
    __shared__ float part[4];
    const int b = blockIdx.x, tid = threadIdx.x;
    float acc = 0.0f;
#pragma unroll
    for (int q = 0; q < 8; ++q) {
        const int k = q * 256 + tid;
        acc = __fmaf_rn(hout[(size_t)b * (Fn * 16) + k], Wf[k], acc);
    }
#pragma unroll
    for (int off = 32; off; off >>= 1) acc += __shfl_down(acc, off, 64);
    if ((tid & 63) == 0) part[tid >> 6] = acc;
    __syncthreads();
    if (tid == 0) out[b] = part[0] + part[1] + part[2] + part[3] + bfu[0];
}

extern "C" void kernel_launch(void* const* d_in, const int* in_sizes, int n_in,
                              void* d_out, int out_size, void* d_ws, size_t ws_size,
                              hipStream_t stream) {
    const float* x      = (const float*)d_in[0];
    const float* Wih    = (const float*)d_in[1];
    const float* Whh    = (const float*)d_in[2];
    const float* bih    = (const float*)d_in[3];
    const float* bhh    = (const float*)d_in[4];
    const float* init_h = (const float*)d_in[5];
    const float* init_c = (const float*)d_in[6];
    const float* Wf     = (const float*)d_in[7];
    const float* bf     = (const float*)d_in[8];
    float* out = (float*)d_out;

    char* ws = (char*)d_ws;
    unsigned* xtp = (unsigned*)ws;                      // (T,F,B) u32 = 134,217,728 B
    float* hout   = (float*)(ws + (size_t)134217728);   // (B, F*16) = 8,388,608 B

    transpose_pack<<<dim3(32, 4, 256), dim3(32, 8), 0, stream>>>(x, xtp);
    lstm_fwd<<<2048, 256, 0, stream>>>(xtp, Wih, Whh, bih, bhh, init_h, init_c, hout);
    fuse_out<<<Bsz, 256, 0, stream>>>(hout, Wf, bf, out);
}

// Round 14
// 501.426 us; speedup vs baseline: 1.6138x; 1.6138x over previous
//
#include <hip/hip_runtime.h>

#define Bsz 1024
#define Tn  256
#define Fn  128

typedef float f32x4 __attribute__((ext_vector_type(4)));
typedef float v2f   __attribute__((ext_vector_type(2)));
typedef short s16x8 __attribute__((ext_vector_type(8)));

#define LOG2E 1.44269504088896f
#define L2E2  2.88539008177793f

__device__ __forceinline__ float frcp(float x)  { return __builtin_amdgcn_rcpf(x); }
__device__ __forceinline__ float fexp2(float x) { return __builtin_amdgcn_exp2f(x); }
__device__ __forceinline__ unsigned bf16bits(float v) {   // RNE f32 -> bf16 bits
    unsigned x = __float_as_uint(v);
    return (x + 0x7FFFu + ((x >> 16) & 1u)) >> 16;
}
__device__ __forceinline__ float fromhi(unsigned hb) { return __uint_as_float(hb << 16); }
__device__ __forceinline__ unsigned cvtpk(float a, float b) {  // low=bf16(a), high=bf16(b)
    unsigned r; asm("v_cvt_pk_bf16_f32 %0, %1, %2" : "=v"(r) : "v"(a), "v"(b)); return r;
}

union FragU { unsigned u[4]; s16x8 v; };

// ---------- packed 2-cell LSTM activation (exp2 domain, HW trans pipe) ----------
// 10 v_exp + 2 pair-shared v_rcp per 2 cells. Bounds: |gi,gf,go|<=15,
// |gg|<=17 (|W|,|h|,|x|,|b| bounds, exp2-scaled) => p3 <= 2^47, pair
// product <= 2^94 — no overflow, no gg clamp needed. cs clamped to
// [-126,40] (c random-walks; protects exp2 domain + rcp product).
__device__ __forceinline__ v2f act_pair(v2f gi, v2f gf, v2f gg, v2f go, v2f& c2) {
    const v2f one = (v2f)1.0f;
    const v2f Ei = {fexp2(gi.x), fexp2(gi.y)};
    const v2f Ef = {fexp2(gf.x), fexp2(gf.y)};
    const v2f Eg = {fexp2(gg.x), fexp2(gg.y)};
    const v2f Eo = {fexp2(go.x), fexp2(go.y)};
    const v2f pf  = one + Ef;
    const v2f pig = (one + Ei) * (one + Eg);
    const v2f p3  = pig * pf;
    const float Rm = frcp(p3.x * p3.y);            // pair-shared reciprocal
    const v2f R3  = {Rm * p3.y, Rm * p3.x};
    const v2f Rf  = pig * R3;                      // sigmoid(f)
    const v2f Rig = pf  * R3;                      // 1/((1+Ei)(1+Eg))
    const v2f cn  = __builtin_elementwise_fma(c2, Rf, (Eg - one) * Rig);
    c2 = cn;
    v2f cs = __builtin_elementwise_min(cn * (v2f)L2E2, (v2f)40.0f);
    cs = __builtin_elementwise_max(cs, (v2f)-126.0f);
    const v2f Ec  = {fexp2(cs.x), fexp2(cs.y)};
    const v2f den = (one + Eo) * (one + Ec);
    const float Rd = frcp(den.x * den.y);          // pair-shared reciprocal
    const v2f Roc = {Rd * den.y, Rd * den.x};
    return (Ec - one) * Roc;                       // o * tanh(c)
}

// ---------- kernel 1: transpose x (B,T,F) f32 -> (T,F,B) packed (lo16<<16 | hi16) ----------
__global__ __launch_bounds__(256) void transpose_pack(const float* __restrict__ x,
                                                      unsigned* __restrict__ xt) {
    __shared__ float tile[32][33];
    const int t  = blockIdx.z;
    const int bb = blockIdx.x * 32;
    const int ff = blockIdx.y * 32;
    const int tx = threadIdx.x;   // 0..31
    const int ty = threadIdx.y;   // 0..7
#pragma unroll
    for (int i = 0; i < 4; ++i) {
        int brow = ty + i * 8;
        tile[brow][tx] = x[((size_t)(bb + brow) * Tn + t) * Fn + (ff + tx)];
    }
    __syncthreads();
#pragma unroll
    for (int i = 0; i < 4; ++i) {
        int frow = ty + i * 8;
        float v = tile[tx][frow];
        unsigned hb = bf16bits(v);
        unsigned lb = bf16bits(v - fromhi(hb));
        xt[((size_t)t * Fn + (ff + frow)) * Bsz + (bb + tx)] = hb | (lb << 16);
    }
}

// ---------- kernel 2: recurrent LSTM via MFMA, zero LDS, 2 tiles/wave ----------
// wave = 1 feature x 32 batches (two independent 16-batch MFMA tiles
// sharing the SAME A-fragments/bias). Two independent MFMA->act->B chains
// per wave double per-wave ILP: when chain A waits on a trans result,
// chain B issues. Fragment math identical to r12 (validated, 4.9e-4):
//   A = [W_hi | gq<2: W_lo; gq2: {wxh,wxh}; gq3: {wxl,0}]
//   B = [h    | gq<2: h;    gq>=2: {x_hi,x_lo}, 0]     C = fp32 bias
__global__ __launch_bounds__(256, 4) void lstm_fwd(const unsigned* __restrict__ xt,  // (T,F,B) packed
                                                   const float* __restrict__ Wih,    // (F,64)
                                                   const float* __restrict__ Whh,    // (F,64,16)
                                                   const float* __restrict__ bih,    // (F,64)
                                                   const float* __restrict__ bhh,    // (F,64)
                                                   const float* __restrict__ init_h,
                                                   const float* __restrict__ init_c,
                                                   float* __restrict__ hout) {       // (B, F*16)
    const int tid  = threadIdx.x;
    const int wv   = tid >> 6;
    const int lane = tid & 63;
    const int gq   = lane >> 4;          // k-quad group / D-row-group
    const int col  = lane & 15;          // A: M-row; B,D: batch col
    const int f    = blockIdx.x >> 3;                  // 0..127
    const int bc2  = ((blockIdx.x & 7) << 2) | wv;     // 0..31 (32-batch group)
    const int bglobA = bc2 * 32 + col;
    const int bglobB = bglobA + 16;

    // ---- persistent fragments (weights pre-scaled into exp2 domain) ----
    s16x8 Aw[4];
    f32x4 biasC[4];
#pragma unroll
    for (int g = 0; g < 4; ++g) {
        const float s = (g == 2) ? L2E2 : -LOG2E;
        const float* wrow = Whh + ((size_t)f * 64 + g * 16 + col) * 16;
        float v0 = wrow[4 * gq + 0] * s, v1 = wrow[4 * gq + 1] * s;
        float v2 = wrow[4 * gq + 2] * s, v3 = wrow[4 * gq + 3] * s;
        unsigned h0 = bf16bits(v0), h1 = bf16bits(v1);
        unsigned h2 = bf16bits(v2), h3 = bf16bits(v3);
        FragU a;
        a.u[0] = h0 | (h1 << 16);        // W_hi quad (plane 0)
        a.u[1] = h2 | (h3 << 16);
        if (gq < 2) {                    // plane 1: W_lo quad
            a.u[2] = bf16bits(v0 - fromhi(h0)) | (bf16bits(v1 - fromhi(h1)) << 16);
            a.u[3] = bf16bits(v2 - fromhi(h2)) | (bf16bits(v3 - fromhi(h3)) << 16);
        } else {                         // plane 1: x-slots
            const float wx = Wih[(size_t)f * 64 + g * 16 + col] * s;
            const unsigned wxh = bf16bits(wx);
            const unsigned wxl = bf16bits(wx - fromhi(wxh));
            a.u[2] = (gq == 2) ? (wxh | (wxh << 16))   // wxh*x_hi + wxh*x_lo
                               : wxl;                  // wxl*x_hi
            a.u[3] = 0u;
        }
        Aw[g] = a.v;
        const size_t bb = (size_t)f * 64 + g * 16 + gq * 4;
        biasC[g] = f32x4{(bih[bb + 0] + bhh[bb + 0]) * s, (bih[bb + 1] + bhh[bb + 1]) * s,
                         (bih[bb + 2] + bhh[bb + 2]) * s, (bih[bb + 3] + bhh[bb + 3]) * s};
    }

    v2f c01a, c23a, h01a, h23a, c01b, c23b, h01b, h23b;
    {
        const int base = f * 16 + gq * 4;
        c01a = c01b = v2f{init_c[base + 0], init_c[base + 1]};
        c23a = c23b = v2f{init_c[base + 2], init_c[base + 3]};
        h01a = h01b = v2f{init_h[base + 0], init_h[base + 1]};
        h23a = h23b = v2f{init_h[base + 2], init_h[base + 3]};
    }

    unsigned p0a = cvtpk(h01a.x, h01a.y), p1a = cvtpk(h23a.x, h23a.y);
    unsigned p0b = cvtpk(h01b.x, h01b.y), p1b = cvtpk(h23b.x, h23b.y);

    const bool hpath = (gq < 2);         // B plane-1 content select
    const unsigned* __restrict__ xp = xt + (size_t)f * Bsz + bglobA;
    unsigned xwA = xp[0];
    unsigned xwB = xp[16];

    for (int t = 0; t < Tn; ++t) {
        const int nxt = (t + 1 < Tn) ? Fn * Bsz : 0;
        const unsigned xnA = xp[nxt];
        const unsigned xnB = xp[nxt + 16];
        xp += Fn * Bsz;

        FragU ba, bb_;
        ba.u[0]  = p0a;  ba.u[1]  = p1a;
        ba.u[2]  = hpath ? p0a : xwA;  ba.u[3]  = hpath ? p1a : 0u;
        bb_.u[0] = p0b;  bb_.u[1] = p1b;
        bb_.u[2] = hpath ? p0b : xwB;  bb_.u[3] = hpath ? p1b : 0u;

        const f32x4 a0 = __builtin_amdgcn_mfma_f32_16x16x32_bf16(Aw[0], ba.v,  biasC[0], 0, 0, 0);
        const f32x4 b0 = __builtin_amdgcn_mfma_f32_16x16x32_bf16(Aw[0], bb_.v, biasC[0], 0, 0, 0);
        const f32x4 a1 = __builtin_amdgcn_mfma_f32_16x16x32_bf16(Aw[1], ba.v,  biasC[1], 0, 0, 0);
        const f32x4 b1 = __builtin_amdgcn_mfma_f32_16x16x32_bf16(Aw[1], bb_.v, biasC[1], 0, 0, 0);
        const f32x4 a2 = __builtin_amdgcn_mfma_f32_16x16x32_bf16(Aw[2], ba.v,  biasC[2], 0, 0, 0);
        const f32x4 b2 = __builtin_amdgcn_mfma_f32_16x16x32_bf16(Aw[2], bb_.v, biasC[2], 0, 0, 0);
        const f32x4 a3 = __builtin_amdgcn_mfma_f32_16x16x32_bf16(Aw[3], ba.v,  biasC[3], 0, 0, 0);
        const f32x4 b3 = __builtin_amdgcn_mfma_f32_16x16x32_bf16(Aw[3], bb_.v, biasC[3], 0, 0, 0);

        h01a = act_pair(__builtin_shufflevector(a0, a0, 0, 1),
                        __builtin_shufflevector(a1, a1, 0, 1),
                        __builtin_shufflevector(a2, a2, 0, 1),
                        __builtin_shufflevector(a3, a3, 0, 1), c01a);
        h01b = act_pair(__builtin_shufflevector(b0, b0, 0, 1),
                        __builtin_shufflevector(b1, b1, 0, 1),
                        __builtin_shufflevector(b2, b2, 0, 1),
                        __builtin_shufflevector(b3, b3, 0, 1), c01b);
        h23a = act_pair(__builtin_shufflevector(a0, a0, 2, 3),
                        __builtin_shufflevector(a1, a1, 2, 3),
                        __builtin_shufflevector(a2, a2, 2, 3),
                        __builtin_shufflevector(a3, a3, 2, 3), c23a);
        h23b = act_pair(__builtin_shufflevector(b0, b0, 2, 3),
                        __builtin_shufflevector(b1, b1, 2, 3),
                        __builtin_shufflevector(b2, b2, 2, 3),
                        __builtin_shufflevector(b3, b3, 2, 3), c23b);

        p0a = cvtpk(h01a.x, h01a.y);  p1a = cvtpk(h23a.x, h23a.y);
        p0b = cvtpk(h01b.x, h01b.y);  p1b = cvtpk(h23b.x, h23b.y);
        xwA = xnA;  xwB = xnB;
    }

    *(f32x4*)(&hout[(size_t)bglobA * (Fn * 16) + f * 16 + gq * 4]) =
        f32x4{h01a.x, h01a.y, h23a.x, h23a.y};
    *(f32x4*)(&hout[(size_t)bglobB * (Fn * 16) + f * 16 + gq * 4]) =
        f32x4{h01b.x, h01b.y, h23b.x, h23b.y};
}

// ---------- kernel 3: out[b] = b_fuse + sum_k hout[b][k]*W_fuse[k] ----------
__global__ __launch_bounds__(256) void fuse_out(const float* __restrict__ hout,
                                                const float* __restrict__ Wf,
                                                const float* __restrict__ bfu,
                                                float* __restrict__ out) {
    __shared__ float part[4];
    const int b = blockIdx.x, tid = threadIdx.x;
    float acc = 0.0f;
#pragma unroll
    for (int q = 0; q < 8; ++q) {
        const int k = q * 256 + tid;
        acc = __fmaf_rn(hout[(size_t)b * (Fn * 16) + k], Wf[k], acc);
    }
#pragma unroll
    for (int off = 32; off; off >>= 1) acc += __shfl_down(acc, off, 64);
    if ((tid & 63) == 0) part[tid >> 6] = acc;
    __syncthreads();
    if (tid == 0) out[b] = part[0] + part[1] + part[2] + part[3] + bfu[0];
}

extern "C" void kernel_launch(void* const* d_in, const int* in_sizes, int n_in,
                              void* d_out, int out_size, void* d_ws, size_t ws_size,
                              hipStream_t stream) {
    const float* x      = (const float*)d_in[0];
    const float* Wih    = (const float*)d_in[1];
    const float* Whh    = (const float*)d_in[2];
    const float* bih    = (const float*)d_in[3];
    const float* bhh    = (const float*)d_in[4];
    const float* init_h = (const float*)d_in[5];
    const float* init_c = (const float*)d_in[6];
    const float* Wf     = (const float*)d_in[7];
    const float* bf     = (const float*)d_in[8];
    float* out = (float*)d_out;

    char* ws = (char*)d_ws;
    unsigned* xtp = (unsigned*)ws;                      // (T,F,B) u32 = 134,217,728 B
    float* hout   = (float*)(ws + (size_t)134217728);   // (B, F*16) = 8,388,608 B

    transpose_pack<<<dim3(32, 4, 256), dim3(32, 8), 0, stream>>>(x, xtp);
    lstm_fwd<<<1024, 256, 0, stream>>>(xtp, Wih, Whh, bih, bhh, init_h, init_c, hout);
    fuse_out<<<Bsz, 256, 0, stream>>>(hout, Wf, bf, out);
}

// Round 15
// 494.618 us; speedup vs baseline: 1.6360x; 1.0138x over previous
//
#include <hip/hip_runtime.h>

#define Bsz 1024
#define Tn  256
#define Fn  128

typedef float f32x4 __attribute__((ext_vector_type(4)));
typedef float v2f   __attribute__((ext_vector_type(2)));
typedef short s16x8 __attribute__((ext_vector_type(8)));

#define LOG2E 1.44269504088896f
#define L2E2  2.88539008177793f

__device__ __forceinline__ float frcp(float x)  { return __builtin_amdgcn_rcpf(x); }
__device__ __forceinline__ float fexp2(float x) { return __builtin_amdgcn_exp2f(x); }
__device__ __forceinline__ unsigned bf16bits(float v) {   // RNE f32 -> bf16 bits
    unsigned x = __float_as_uint(v);
    return (x + 0x7FFFu + ((x >> 16) & 1u)) >> 16;
}
__device__ __forceinline__ float fromhi(unsigned hb) { return __uint_as_float(hb << 16); }
__device__ __forceinline__ unsigned cvtpk(float a, float b) {  // low=bf16(a), high=bf16(b)
    unsigned r; asm("v_cvt_pk_bf16_f32 %0, %1, %2" : "=v"(r) : "v"(a), "v"(b)); return r;
}

union FragU { unsigned u[4]; s16x8 v; };

// ---------- packed 2-cell LSTM activation (exp2 domain, HW trans pipe) ----------
// 10 v_exp + 2 pair-shared v_rcp per 2 cells (validated r12-r14, 4.9e-4).
__device__ __forceinline__ v2f act_pair(v2f gi, v2f gf, v2f gg, v2f go, v2f& c2) {
    const v2f one = (v2f)1.0f;
    const v2f Ei = {fexp2(gi.x), fexp2(gi.y)};
    const v2f Ef = {fexp2(gf.x), fexp2(gf.y)};
    const v2f Eg = {fexp2(gg.x), fexp2(gg.y)};
    const v2f Eo = {fexp2(go.x), fexp2(go.y)};
    const v2f pf  = one + Ef;
    const v2f pig = (one + Ei) * (one + Eg);
    const v2f p3  = pig * pf;
    const float Rm = frcp(p3.x * p3.y);            // pair-shared reciprocal
    const v2f R3  = {Rm * p3.y, Rm * p3.x};
    const v2f Rf  = pig * R3;                      // sigmoid(f)
    const v2f Rig = pf  * R3;                      // 1/((1+Ei)(1+Eg))
    const v2f cn  = __builtin_elementwise_fma(c2, Rf, (Eg - one) * Rig);
    c2 = cn;
    v2f cs = __builtin_elementwise_min(cn * (v2f)L2E2, (v2f)40.0f);
    cs = __builtin_elementwise_max(cs, (v2f)-126.0f);
    const v2f Ec  = {fexp2(cs.x), fexp2(cs.y)};
    const v2f den = (one + Eo) * (one + Ec);
    const float Rd = frcp(den.x * den.y);          // pair-shared reciprocal
    const v2f Roc = {Rd * den.y, Rd * den.x};
    return (Ec - one) * Roc;                       // o * tanh(c)
}

// ---------- kernel 1: transpose x (B,T,F) f32 -> (T,F,B) packed (lo16<<16 | hi16) ----------
__global__ __launch_bounds__(256) void transpose_pack(const float* __restrict__ x,
                                                      unsigned* __restrict__ xt) {
    __shared__ float tile[32][33];
    const int t  = blockIdx.z;
    const int bb = blockIdx.x * 32;
    const int ff = blockIdx.y * 32;
    const int tx = threadIdx.x;   // 0..31
    const int ty = threadIdx.y;   // 0..7
#pragma unroll
    for (int i = 0; i < 4; ++i) {
        int brow = ty + i * 8;
        tile[brow][tx] = x[((size_t)(bb + brow) * Tn + t) * Fn + (ff + tx)];
    }
    __syncthreads();
#pragma unroll
    for (int i = 0; i < 4; ++i) {
        int frow = ty + i * 8;
        float v = tile[tx][frow];
        unsigned hb = bf16bits(v);
        unsigned lb = bf16bits(v - fromhi(hb));
        xt[((size_t)t * Fn + (ff + frow)) * Bsz + (bb + tx)] = hb | (lb << 16);
    }
}

// ---------- kernel 2: recurrent LSTM via MFMA, zero LDS, 4 tiles/wave ----------
// wave = 1 feature x 64 batches (four independent 16-batch MFMA tiles
// sharing the SAME A-fragments/bias). 8 independent MFMA->act chains per
// wave; grid 512 blocks = 2 waves/SIMD (grid-limited). Fragment math
// identical to r12-r14 (validated, absmax 4.9e-4).
__global__ __launch_bounds__(256, 2) void lstm_fwd(const unsigned* __restrict__ xt,  // (T,F,B) packed
                                                   const float* __restrict__ Wih,    // (F,64)
                                                   const float* __restrict__ Whh,    // (F,64,16)
                                                   const float* __restrict__ bih,    // (F,64)
                                                   const float* __restrict__ bhh,    // (F,64)
                                                   const float* __restrict__ init_h,
                                                   const float* __restrict__ init_c,
                                                   float* __restrict__ hout) {       // (B, F*16)
    const int tid  = threadIdx.x;
    const int wv   = tid >> 6;
    const int lane = tid & 63;
    const int gq   = lane >> 4;          // k-quad group / D-row-group
    const int col  = lane & 15;          // A: M-row; B,D: batch col
    const int f    = blockIdx.x >> 2;                  // 0..127
    const int bc4  = ((blockIdx.x & 3) << 2) | wv;     // 0..15 (64-batch group)
    const int bbase = bc4 * 64 + col;

    // ---- persistent fragments (weights pre-scaled into exp2 domain) ----
    s16x8 Aw[4];
    f32x4 biasC[4];
#pragma unroll
    for (int g = 0; g < 4; ++g) {
        const float s = (g == 2) ? L2E2 : -LOG2E;
        const float* wrow = Whh + ((size_t)f * 64 + g * 16 + col) * 16;
        float v0 = wrow[4 * gq + 0] * s, v1 = wrow[4 * gq + 1] * s;
        float v2 = wrow[4 * gq + 2] * s, v3 = wrow[4 * gq + 3] * s;
        unsigned h0 = bf16bits(v0), h1 = bf16bits(v1);
        unsigned h2 = bf16bits(v2), h3 = bf16bits(v3);
        FragU a;
        a.u[0] = h0 | (h1 << 16);        // W_hi quad (plane 0)
        a.u[1] = h2 | (h3 << 16);
        if (gq < 2) {                    // plane 1: W_lo quad
            a.u[2] = bf16bits(v0 - fromhi(h0)) | (bf16bits(v1 - fromhi(h1)) << 16);
            a.u[3] = bf16bits(v2 - fromhi(h2)) | (bf16bits(v3 - fromhi(h3)) << 16);
        } else {                         // plane 1: x-slots
            const float wx = Wih[(size_t)f * 64 + g * 16 + col] * s;
            const unsigned wxh = bf16bits(wx);
            const unsigned wxl = bf16bits(wx - fromhi(wxh));
            a.u[2] = (gq == 2) ? (wxh | (wxh << 16))   // wxh*x_hi + wxh*x_lo
                               : wxl;                  // wxl*x_hi
            a.u[3] = 0u;
        }
        Aw[g] = a.v;
        const size_t bb = (size_t)f * 64 + g * 16 + gq * 4;
        biasC[g] = f32x4{(bih[bb + 0] + bhh[bb + 0]) * s, (bih[bb + 1] + bhh[bb + 1]) * s,
                         (bih[bb + 2] + bhh[bb + 2]) * s, (bih[bb + 3] + bhh[bb + 3]) * s};
    }

    v2f c01[4], c23[4];
    unsigned p0[4], p1[4], xw[4];
    {
        const int base = f * 16 + gq * 4;
        const v2f ic01 = v2f{init_c[base + 0], init_c[base + 1]};
        const v2f ic23 = v2f{init_c[base + 2], init_c[base + 3]};
        const unsigned ip0 = cvtpk(init_h[base + 0], init_h[base + 1]);
        const unsigned ip1 = cvtpk(init_h[base + 2], init_h[base + 3]);
#pragma unroll
        for (int k = 0; k < 4; ++k) {
            c01[k] = ic01;  c23[k] = ic23;
            p0[k] = ip0;    p1[k] = ip1;
        }
    }

    const bool hpath = (gq < 2);         // B plane-1 content select
    const unsigned* __restrict__ xp = xt + (size_t)f * Bsz + bbase;
#pragma unroll
    for (int k = 0; k < 4; ++k) xw[k] = xp[16 * k];

    for (int t = 0; t < Tn; ++t) {
        const int nxt = (t + 1 < Tn) ? Fn * Bsz : 0;
        unsigned xn[4];
#pragma unroll
        for (int k = 0; k < 4; ++k) xn[k] = xp[nxt + 16 * k];
        xp += Fn * Bsz;

        f32x4 acc[4][4];
#pragma unroll
        for (int k = 0; k < 4; ++k) {
            FragU b;
            b.u[0] = p0[k];
            b.u[1] = p1[k];
            b.u[2] = hpath ? p0[k] : xw[k];
            b.u[3] = hpath ? p1[k] : 0u;
#pragma unroll
            for (int g = 0; g < 4; ++g)
                acc[k][g] = __builtin_amdgcn_mfma_f32_16x16x32_bf16(Aw[g], b.v, biasC[g], 0, 0, 0);
        }

#pragma unroll
        for (int k = 0; k < 4; ++k) {
            const v2f h01 = act_pair(
                __builtin_shufflevector(acc[k][0], acc[k][0], 0, 1),
                __builtin_shufflevector(acc[k][1], acc[k][1], 0, 1),
                __builtin_shufflevector(acc[k][2], acc[k][2], 0, 1),
                __builtin_shufflevector(acc[k][3], acc[k][3], 0, 1), c01[k]);
            const v2f h23 = act_pair(
                __builtin_shufflevector(acc[k][0], acc[k][0], 2, 3),
                __builtin_shufflevector(acc[k][1], acc[k][1], 2, 3),
                __builtin_shufflevector(acc[k][2], acc[k][2], 2, 3),
                __builtin_shufflevector(acc[k][3], acc[k][3], 2, 3), c23[k]);
            p0[k] = cvtpk(h01.x, h01.y);
            p1[k] = cvtpk(h23.x, h23.y);
            xw[k] = xn[k];
        }
    }

    // final h: reconstruct from bf16 packs (h stored as bf16 in p-words is
    // NOT enough precision for output) -> keep exact: recompute from last
    // act values. We stored only packs; instead store exact h per tile:
    // (packs are bf16-rounded; output threshold needs exact) — so stash h
    // exactly at the last step via a second pass below.
    // To keep registers low we redo the last step's output from p/c is not
    // possible; instead we saved nothing extra: write bf16-rounded h.
    // bf16 rounding of h adds <= 3.9e-3 * 0.004 scale... NOT acceptable.
    // => write exact h: we still have c, and h = f(c, o-gate) lost. So we
    // instead keep the exact final h in registers (h01/h23 of last iter).
    // Implemented by peeling the last iteration:
    // (handled above: the loop's final h01/h23 were consumed into p0/p1;
    //  recover exact h from the LAST act_pair by re-running it is costly.
    //  Simplest correct: store h from bf16 packs is wrong; so we peel.)
    // --- NOTE: to avoid complexity, the loop above runs T-1 steps and the
    // final step is peeled here with exact h kept. ---
    {
        // the loop actually ran all T steps; p-words hold bf16(h_T).
        // Recover exact h_T by one extra activation replay is not possible
        // without the last accs. Instead: write from packs PLUS stored c to
        // hout is wrong. => We re-derive exact h via the saved exact values:
    }
    // Exact final h storage: the last loop iteration's h01/h23 values are
    // needed; restructure minimally by recomputing them from the final
    // p-words is lossy. Therefore the loop was compiled with t<Tn and we
    // accept bf16-rounded OUTPUT ONLY IF error budget allows. It does not.
    // => Use the peeled-last-step values stashed below.
    // (See stash: we overwrite hout from inside the loop's last iteration.)
    if (true) {} // placeholder; actual store happens in-loop at t==Tn-1 via
                 // the exact h values (see below duplicate of act block).
    // --- The above convoluted path is replaced by a clean approach: the
    // main loop stores exact h when t == Tn-1 (uniform branch, once). ---
    (void)0;
}

// The in-loop store variant requires h01/h23 visibility; simplest is a tiny
// epilogue kernel reading nothing. To keep this file clean and correct, the
// store was folded into the loop via the t==Tn-1 branch in a refactored
// kernel below. (lstm_fwd above is NOT launched.)

// ---------- kernel 2 (launched): same as above with exact-h store in-loop ----------
__global__ __launch_bounds__(256, 2) void lstm_fwd2(const unsigned* __restrict__ xt,
                                                    const float* __restrict__ Wih,
                                                    const float* __restrict__ Whh,
                                                    const float* __restrict__ bih,
                                                    const float* __restrict__ bhh,
                                                    const float* __restrict__ init_h,
                                                    const float* __restrict__ init_c,
                                                    float* __restrict__ hout) {
    const int tid  = threadIdx.x;
    const int wv   = tid >> 6;
    const int lane = tid & 63;
    const int gq   = lane >> 4;
    const int col  = lane & 15;
    const int f    = blockIdx.x >> 2;
    const int bc4  = ((blockIdx.x & 3) << 2) | wv;
    const int bbase = bc4 * 64 + col;

    s16x8 Aw[4];
    f32x4 biasC[4];
#pragma unroll
    for (int g = 0; g < 4; ++g) {
        const float s = (g == 2) ? L2E2 : -LOG2E;
        const float* wrow = Whh + ((size_t)f * 64 + g * 16 + col) * 16;
        float v0 = wrow[4 * gq + 0] * s, v1 = wrow[4 * gq + 1] * s;
        float v2 = wrow[4 * gq + 2] * s, v3 = wrow[4 * gq + 3] * s;
        unsigned h0 = bf16bits(v0), h1 = bf16bits(v1);
        unsigned h2 = bf16bits(v2), h3 = bf16bits(v3);
        FragU a;
        a.u[0] = h0 | (h1 << 16);
        a.u[1] = h2 | (h3 << 16);
        if (gq < 2) {
            a.u[2] = bf16bits(v0 - fromhi(h0)) | (bf16bits(v1 - fromhi(h1)) << 16);
            a.u[3] = bf16bits(v2 - fromhi(h2)) | (bf16bits(v3 - fromhi(h3)) << 16);
        } else {
            const float wx = Wih[(size_t)f * 64 + g * 16 + col] * s;
            const unsigned wxh = bf16bits(wx);
            const unsigned wxl = bf16bits(wx - fromhi(wxh));
            a.u[2] = (gq == 2) ? (wxh | (wxh << 16)) : wxl;
            a.u[3] = 0u;
        }
        Aw[g] = a.v;
        const size_t bb = (size_t)f * 64 + g * 16 + gq * 4;
        biasC[g] = f32x4{(bih[bb + 0] + bhh[bb + 0]) * s, (bih[bb + 1] + bhh[bb + 1]) * s,
                         (bih[bb + 2] + bhh[bb + 2]) * s, (bih[bb + 3] + bhh[bb + 3]) * s};
    }

    v2f c01[4], c23[4];
    unsigned p0[4], p1[4], xw[4];
    {
        const int base = f * 16 + gq * 4;
        const v2f ic01 = v2f{init_c[base + 0], init_c[base + 1]};
        const v2f ic23 = v2f{init_c[base + 2], init_c[base + 3]};
        const unsigned ip0 = cvtpk(init_h[base + 0], init_h[base + 1]);
        const unsigned ip1 = cvtpk(init_h[base + 2], init_h[base + 3]);
#pragma unroll
        for (int k = 0; k < 4; ++k) {
            c01[k] = ic01;  c23[k] = ic23;
            p0[k] = ip0;    p1[k] = ip1;
        }
    }

    const bool hpath = (gq < 2);
    const unsigned* __restrict__ xp = xt + (size_t)f * Bsz + bbase;
#pragma unroll
    for (int k = 0; k < 4; ++k) xw[k] = xp[16 * k];

    for (int t = 0; t < Tn; ++t) {
        const int nxt = (t + 1 < Tn) ? Fn * Bsz : 0;
        unsigned xn[4];
#pragma unroll
        for (int k = 0; k < 4; ++k) xn[k] = xp[nxt + 16 * k];
        xp += Fn * Bsz;

        f32x4 acc[4][4];
#pragma unroll
        for (int k = 0; k < 4; ++k) {
            FragU b;
            b.u[0] = p0[k];
            b.u[1] = p1[k];
            b.u[2] = hpath ? p0[k] : xw[k];
            b.u[3] = hpath ? p1[k] : 0u;
#pragma unroll
            for (int g = 0; g < 4; ++g)
                acc[k][g] = __builtin_amdgcn_mfma_f32_16x16x32_bf16(Aw[g], b.v, biasC[g], 0, 0, 0);
        }

        const bool last = (t == Tn - 1);
#pragma unroll
        for (int k = 0; k < 4; ++k) {
            const v2f h01 = act_pair(
                __builtin_shufflevector(acc[k][0], acc[k][0], 0, 1),
                __builtin_shufflevector(acc[k][1], acc[k][1], 0, 1),
                __builtin_shufflevector(acc[k][2], acc[k][2], 0, 1),
                __builtin_shufflevector(acc[k][3], acc[k][3], 0, 1), c01[k]);
            const v2f h23 = act_pair(
                __builtin_shufflevector(acc[k][0], acc[k][0], 2, 3),
                __builtin_shufflevector(acc[k][1], acc[k][1], 2, 3),
                __builtin_shufflevector(acc[k][2], acc[k][2], 2, 3),
                __builtin_shufflevector(acc[k][3], acc[k][3], 2, 3), c23[k]);
            p0[k] = cvtpk(h01.x, h01.y);
            p1[k] = cvtpk(h23.x, h23.y);
            xw[k] = xn[k];
            if (last) {
                *(f32x4*)(&hout[(size_t)(bbase + 16 * k) * (Fn * 16) + f * 16 + gq * 4]) =
                    f32x4{h01.x, h01.y, h23.x, h23.y};
            }
        }
    }
}

// ---------- kernel 3: out[b] = b_fuse + sum_k hout[b][k]*W_fuse[k] ----------
__global__ __launch_bounds__(256) void fuse_out(const float* __restrict__ hout,
                                                const float* __restrict__ Wf,
                                                const float* __restrict__ bfu,
                                                float* __restrict__ out) {
    __shared__ float part[4];
    const int b = blockIdx.x, tid = threadIdx.x;
    float acc = 0.0f;
#pragma unroll
    for (int q = 0; q < 8; ++q) {
        const int k = q * 256 + tid;
        acc = __fmaf_rn(hout[(size_t)b * (Fn * 16) + k], Wf[k], acc);
    }
#pragma unroll
    for (int off = 32; off; off >>= 1) acc += __shfl_down(acc, off, 64);
    if ((tid & 63) == 0) part[tid >> 6] = acc;
    __syncthreads();
    if (tid == 0) out[b] = part[0] + part[1] + part[2] + part[3] + bfu[0];
}

extern "C" void kernel_launch(void* const* d_in, const int* in_sizes, int n_in,
                              void* d_out, int out_size, void* d_ws, size_t ws_size,
                              hipStream_t stream) {
    const float* x      = (const float*)d_in[0];
    const float* Wih    = (const float*)d_in[1];
    const float* Whh    = (const float*)d_in[2];
    const float* bih    = (const float*)d_in[3];
    const float* bhh    = (const float*)d_in[4];
    const float* init_h = (const float*)d_in[5];
    const float* init_c = (const float*)d_in[6];
    const float* Wf     = (const float*)d_in[7];
    const float* bf     = (const float*)d_in[8];
    float* out = (float*)d_out;

    char* ws = (char*)d_ws;
    unsigned* xtp = (unsigned*)ws;                      // (T,F,B) u32 = 134,217,728 B
    float* hout   = (float*)(ws + (size_t)134217728);   // (B, F*16) = 8,388,608 B

    transpose_pack<<<dim3(32, 4, 256), dim3(32, 8), 0, stream>>>(x, xtp);
    lstm_fwd2<<<512, 256, 0, stream>>>(xtp, Wih, Whh, bih, bhh, init_h, init_c, hout);
    fuse_out<<<Bsz, 256, 0, stream>>>(hout, Wf, bf, out);
}